// Round 5
// baseline (1029.684 us; speedup 1.0000x reference)
//
#include <hip/hip_runtime.h>
#include <hip/hip_bf16.h>

#define HID 512
#define EMB 512
#define KTOP 8
#define BM 64
#define THREADS 1024
#define POWN (HID * EMB)   // 262144 elements per power matrix

typedef __attribute__((ext_vector_type(8))) short bf16x8;
typedef __attribute__((ext_vector_type(4))) float f32x4;
typedef __attribute__((ext_vector_type(4))) unsigned u32x4;

// ---- manual bf16 conversion (RNE), trivially-copyable types only ----------
__device__ __forceinline__ short f2bf(float f) {
    unsigned u = __builtin_bit_cast(unsigned, f);
    u += 0x7fffu + ((u >> 16) & 1u);          // round-to-nearest-even
    return (short)(u >> 16);
}
__device__ __forceinline__ float bf2f(short s) {
    unsigned u = ((unsigned)(unsigned short)s) << 16;
    return __builtin_bit_cast(float, u);
}
__device__ __forceinline__ unsigned cvtpk2(float x, float y) {
    return ((unsigned)(unsigned short)f2bf(x)) |
           (((unsigned)(unsigned short)f2bf(y)) << 16);
}
__device__ __forceinline__ bf16x8 pack8(f32x4 a, f32x4 b) {
    u32x4 r = {cvtpk2(a[0], a[1]), cvtpk2(a[2], a[3]),
               cvtpk2(b[0], b[1]), cvtpk2(b[2], b[3])};
    return __builtin_bit_cast(bf16x8, r);
}
__device__ __forceinline__ void split_bf(float w, short& hi, short& lo) {
    hi = f2bf(w);
    lo = f2bf(w - bf2f(hi));
}

// ---------------------------------------------------------------------------
// Kernel 0: split Wa (= M1) into hi/lo bf16, row-major AND transposed; Ua->bf16.
__global__ void prep_kernel(const float* __restrict__ Wa, const float* __restrict__ Ua,
                            short* __restrict__ hiRM, short* __restrict__ loRM,
                            short* __restrict__ hiT, short* __restrict__ loT,
                            short* __restrict__ ua_b) {
    int i = blockIdx.x * blockDim.x + threadIdx.x;
    if (i >= POWN) return;
    int r = i >> 9, c = i & 511;
    short hi, lo;
    split_bf(Wa[i], hi, lo);
    hiRM[i] = hi; loRM[i] = lo;
    hiT[c * 512 + r] = hi;        // T layout: T[k][e] = M[e][k]
    loT[c * 512 + r] = lo;
    ua_b[i] = f2bf(Ua[i]);
}

__device__ __forceinline__ int sel4(int4 v, int i) {
    int r = v.x;
    if (i == 1) r = v.y;
    if (i == 2) r = v.z;
    if (i == 3) r = v.w;
    return r;
}

// ---------------------------------------------------------------------------
// Kernel 1: batched matrix-power products. D = A * B, 512x512x512, split-bf16
// 3-pass (Ahi*Bhi + Ahi*Blo + Alo*Bhi). A read row-major hi/lo; B read from the
// transposed hi/lo copies. Output written hi/lo RM, plus T copies for slots<4.
__global__ __launch_bounds__(256)
void powmul_kernel(short* __restrict__ hiRM, short* __restrict__ loRM,
                   short* __restrict__ hiT, short* __restrict__ loT,
                   int4 aS, int4 bS, int4 dS) {
    const int p = blockIdx.z;
    const int as = sel4(aS, p), bs = sel4(bS, p), ds = sel4(dS, p);
    const short* Ah = hiRM + (size_t)as * POWN;
    const short* Al = loRM + (size_t)as * POWN;
    const short* Bh = hiT + (size_t)bs * POWN;
    const short* Bl = loT + (size_t)bs * POWN;

    const int tid = threadIdx.x, lane = tid & 63, w = tid >> 6;
    const int l15 = lane & 15, lg = lane >> 4;
    const int row = blockIdx.x * 64 + w * 16 + l15;
    const int colb = blockIdx.y * 64;

    f32x4 acc[4];
#pragma unroll
    for (int nf = 0; nf < 4; ++nf) acc[nf] = (f32x4){0.f, 0.f, 0.f, 0.f};

    for (int ch = 0; ch < 16; ++ch) {
        const int e0 = ch * 32 + lg * 8;
        bf16x8 ah = *(const bf16x8*)(Ah + row * 512 + e0);
        bf16x8 al = *(const bf16x8*)(Al + row * 512 + e0);
#pragma unroll
        for (int nf = 0; nf < 4; ++nf) {
            const int col = colb + nf * 16 + l15;
            bf16x8 bh = *(const bf16x8*)(Bh + col * 512 + e0);
            bf16x8 bl = *(const bf16x8*)(Bl + col * 512 + e0);
            acc[nf] = __builtin_amdgcn_mfma_f32_16x16x32_bf16(ah, bh, acc[nf], 0, 0, 0);
            acc[nf] = __builtin_amdgcn_mfma_f32_16x16x32_bf16(ah, bl, acc[nf], 0, 0, 0);
            acc[nf] = __builtin_amdgcn_mfma_f32_16x16x32_bf16(al, bh, acc[nf], 0, 0, 0);
        }
    }

    short* Dh = hiRM + (size_t)ds * POWN;
    short* Dl = loRM + (size_t)ds * POWN;
#pragma unroll
    for (int nf = 0; nf < 4; ++nf)
#pragma unroll
        for (int j = 0; j < 4; ++j) {
            // C/D layout: col = l15, row = lg*4 + j
            int rg = blockIdx.x * 64 + w * 16 + lg * 4 + j;
            int cg = colb + nf * 16 + l15;
            short hi, lo;
            split_bf(acc[nf][j], hi, lo);
            Dh[rg * 512 + cg] = hi;
            Dl[rg * 512 + cg] = lo;
            if (ds < 4) {
                hiT[(size_t)ds * POWN + cg * 512 + rg] = hi;
                loT[(size_t)ds * POWN + cg * 512 + rg] = lo;
            }
        }
}

// ---------------------------------------------------------------------------
// Kernel 2: fully parallel scores + softmax + mt. No inter-step dependency:
// step i uses precomputed M_{i+1} = Wa^{i+1}. x = q@M^T + t_i@Ua^T accumulated
// into ONE set of frags (sum of two GEMMs). 2-pass q (qhi*Whi + qhi*Wlo),
// 1-pass pk. qhi staged in LDS once (64 KB, XOR-swizzled 16B slots).
__global__ __launch_bounds__(THREADS, 4)
void attn_main_kernel(const float* __restrict__ query,
                      const float* __restrict__ topics,
                      const float* __restrict__ cov,
                      const short* __restrict__ pow_hi,
                      const short* __restrict__ pow_lo,
                      const short* __restrict__ ua_b,
                      const float* __restrict__ va_w,
                      const float* __restrict__ va_b,
                      float* __restrict__ out_mt,
                      float* __restrict__ out_alpha) {
    __shared__ short q_lds[BM * HID];          // 64 KB bf16 (hi only)
    __shared__ float sc_part[8][KTOP][BM];     // 16 KB
    __shared__ float scores_s[BM][KTOP];
    __shared__ float alpha_s[BM][KTOP];

    const int tid  = threadIdx.x;
    const int lane = tid & 63;
    const int wave = tid >> 6;      // 0..15
    const int wm   = wave >> 3;     // 0..1  (32 rows)
    const int wn   = wave & 7;      // 0..7  (64 cols)
    const int l15  = lane & 15;
    const int lg   = lane >> 4;
    const long rbase = (long)blockIdx.x * BM;

    // stage qhi -> LDS, converted ONCE. 16B slot s of row r stored at s^(r&7).
    for (int i = tid; i < BM * 64; i += THREADS) {
        int r = i >> 6, s = i & 63;
        const float* qp = query + (rbase + r) * HID + s * 8;
        f32x4 a = *(const f32x4*)qp;
        f32x4 b = *(const f32x4*)(qp + 4);
        *(bf16x8*)&q_lds[(r * 64 + (s ^ (r & 7))) * 8] = pack8(a, b);
    }

    float va_reg[4];
#pragma unroll
    for (int nf = 0; nf < 4; ++nf) va_reg[nf] = va_w[wn * 64 + nf * 16 + l15];
    const float vab = va_b[0];
    const int arow0 = wm * 32 + l15;

    __syncthreads();

#pragma unroll 1
    for (int step = 0; step < KTOP; ++step) {
        f32x4 acc[2][4];
#pragma unroll
        for (int mf = 0; mf < 2; ++mf)
#pragma unroll
            for (int nf = 0; nf < 4; ++nf) acc[mf][nf] = (f32x4){0.f, 0.f, 0.f, 0.f};

        const short* wh = pow_hi + (size_t)step * POWN;
        const short* wl = pow_lo + (size_t)step * POWN;
        const float* tp0 = topics + ((rbase + arow0) * KTOP + step) * EMB;
        const float* tp1 = tp0 + (long)16 * KTOP * EMB;

        for (int ch = 0; ch < 16; ++ch) {
            const int k0 = ch * 32 + lg * 8;
            const int slot = ch * 4 + lg;
            bf16x8 qh[2], tf[2];
#pragma unroll
            for (int mf = 0; mf < 2; ++mf) {
                const int r = arow0 + mf * 16;
                qh[mf] = *(const bf16x8*)&q_lds[(r * 64 + (slot ^ (r & 7))) * 8];
                const float* tp = mf ? tp1 : tp0;
                f32x4 ta = *(const f32x4*)(tp + k0);
                f32x4 tb = *(const f32x4*)(tp + k0 + 4);
                tf[mf] = pack8(ta, tb);
            }
            const int nbase = (wn * 64 + l15) * EMB + k0;
#pragma unroll
            for (int nf = 0; nf < 4; ++nf) {
                const int off = nbase + nf * 16 * EMB;
                bf16x8 whf = *(const bf16x8*)(wh + off);
                bf16x8 wlf = *(const bf16x8*)(wl + off);
                bf16x8 ub  = *(const bf16x8*)(ua_b + off);
#pragma unroll
                for (int mf = 0; mf < 2; ++mf) {
                    acc[mf][nf] = __builtin_amdgcn_mfma_f32_16x16x32_bf16(qh[mf], whf, acc[mf][nf], 0, 0, 0);
                    acc[mf][nf] = __builtin_amdgcn_mfma_f32_16x16x32_bf16(qh[mf], wlf, acc[mf][nf], 0, 0, 0);
                    acc[mf][nf] = __builtin_amdgcn_mfma_f32_16x16x32_bf16(tf[mf], ub,  acc[mf][nf], 0, 0, 0);
                }
            }
        }

        // epilogue: partial score = sum_h tanh(x) * va over this wave's 64 cols
        float part[2][4];
#pragma unroll
        for (int mf = 0; mf < 2; ++mf)
#pragma unroll
            for (int j = 0; j < 4; ++j) part[mf][j] = 0.f;
#pragma unroll
        for (int mf = 0; mf < 2; ++mf)
#pragma unroll
            for (int nf = 0; nf < 4; ++nf)
#pragma unroll
                for (int j = 0; j < 4; ++j) {
                    float x = acc[mf][nf][j];
                    float e = __expf(2.f * x);
                    float th = 1.f - 2.f / (e + 1.f);   // tanh(x)
                    part[mf][j] += th * va_reg[nf];
                }
#pragma unroll
        for (int m = 8; m >= 1; m >>= 1)
#pragma unroll
            for (int mf = 0; mf < 2; ++mf)
#pragma unroll
                for (int j = 0; j < 4; ++j)
                    part[mf][j] += __shfl_xor(part[mf][j], m, 64);
        if (l15 == 0) {
#pragma unroll
            for (int mf = 0; mf < 2; ++mf)
#pragma unroll
                for (int j = 0; j < 4; ++j)
                    sc_part[wn][step][wm * 32 + mf * 16 + lg * 4 + j] = part[mf][j];
        }
        // no barrier: each wave owns its sc_part[wn] slice; steps independent
    }

    __syncthreads();
    if (tid < BM * KTOP) {   // 512 threads: combine 8 N-wave partials
        int r = tid >> 3, st = tid & 7;
        float s = vab;
#pragma unroll
        for (int w = 0; w < 8; ++w) s += sc_part[w][st][r];
        scores_s[r][st] = s * cov[(rbase + r) * KTOP + st];
    }
    __syncthreads();
    if (tid < BM) {
        float mx = scores_s[tid][0];
#pragma unroll
        for (int k = 1; k < KTOP; ++k) mx = fmaxf(mx, scores_s[tid][k]);
        float e[KTOP], sum = 0.f;
#pragma unroll
        for (int k = 0; k < KTOP; ++k) { e[k] = __expf(scores_s[tid][k] - mx); sum += e[k]; }
#pragma unroll
        for (int k = 0; k < KTOP; ++k) {
            float a = e[k] / sum;
            alpha_s[tid][k] = a;
            out_alpha[(rbase + tid) * KTOP + k] = a;
        }
    }
    __syncthreads();

    // mt = sum_k alpha_k * topics[:,k,:]
    for (int i = tid; i < BM * (EMB / 4); i += THREADS) {
        int r = i >> 7;
        int c4 = i & 127;
        const float* tb = topics + (rbase + r) * KTOP * EMB + c4 * 4;
        f32x4 acc = {0.f, 0.f, 0.f, 0.f};
#pragma unroll
        for (int k = 0; k < KTOP; ++k) {
            f32x4 t = *(const f32x4*)(tb + k * EMB);
            float a = alpha_s[r][k];
            acc[0] += t[0] * a;
            acc[1] += t[1] * a;
            acc[2] += t[2] * a;
            acc[3] += t[3] * a;
        }
        *(f32x4*)(out_mt + (rbase + r) * EMB + c4 * 4) = acc;
    }
}

extern "C" void kernel_launch(void* const* d_in, const int* in_sizes, int n_in,
                              void* d_out, int out_size, void* d_ws, size_t ws_size,
                              hipStream_t stream) {
    const float* query  = (const float*)d_in[0];
    const float* topics = (const float*)d_in[1];
    const float* cov    = (const float*)d_in[2];
    const float* Ua     = (const float*)d_in[3];
    const float* Wa     = (const float*)d_in[4];
    const float* va     = (const float*)d_in[5];
    const float* vab    = (const float*)d_in[6];

    const int Brows = in_sizes[0] / HID;   // 16384

    // ws layout: pow_hi RM[8] | pow_lo RM[8] | powT_hi[4] | powT_lo[4] | ua_b
    short* pow_hi = (short*)d_ws;
    short* pow_lo = pow_hi + (size_t)8 * POWN;
    short* powT_h = pow_lo + (size_t)8 * POWN;
    short* powT_l = powT_h + (size_t)4 * POWN;
    short* ua_b   = powT_l + (size_t)4 * POWN;   // total ~12.5 MB

    float* out_mt    = (float*)d_out;
    float* out_alpha = out_mt + (size_t)Brows * EMB;

    prep_kernel<<<(POWN + 255) / 256, 256, 0, stream>>>(Wa, Ua, pow_hi, pow_lo,
                                                        powT_h, powT_l, ua_b);
    // M2 = M1*M1
    powmul_kernel<<<dim3(8, 8, 1), 256, 0, stream>>>(pow_hi, pow_lo, powT_h, powT_l,
        make_int4(0, 0, 0, 0), make_int4(0, 0, 0, 0), make_int4(1, 0, 0, 0));
    // M3 = M2*M1, M4 = M2*M2
    powmul_kernel<<<dim3(8, 8, 2), 256, 0, stream>>>(pow_hi, pow_lo, powT_h, powT_l,
        make_int4(1, 1, 0, 0), make_int4(0, 1, 0, 0), make_int4(2, 3, 0, 0));
    // M5 = M4*M1, M6 = M4*M2, M7 = M3*M4, M8 = M4*M4
    powmul_kernel<<<dim3(8, 8, 4), 256, 0, stream>>>(pow_hi, pow_lo, powT_h, powT_l,
        make_int4(3, 3, 2, 3), make_int4(0, 1, 3, 3), make_int4(4, 5, 6, 7));

    attn_main_kernel<<<Brows / BM, THREADS, 0, stream>>>(query, topics, cov,
                                                         pow_hi, pow_lo, ua_b,
                                                         va, vab, out_mt, out_alpha);
}

// Round 6
// 401.316 us; speedup vs baseline: 2.5658x; 2.5658x over previous
//
#include <hip/hip_runtime.h>
#include <hip/hip_bf16.h>

#define HID 512
#define EMB 512
#define KTOP 8
#define BM 64
#define THREADS 1024
#define POWN (512 * 512)   // elements per 512x512 matrix

typedef __attribute__((ext_vector_type(8))) short bf16x8;
typedef __attribute__((ext_vector_type(4))) float f32x4;
typedef __attribute__((ext_vector_type(4))) unsigned u32x4;

// ---- manual bf16 conversion (RNE), trivially-copyable types only ----------
__device__ __forceinline__ short f2bf(float f) {
    unsigned u = __builtin_bit_cast(unsigned, f);
    u += 0x7fffu + ((u >> 16) & 1u);
    return (short)(u >> 16);
}
__device__ __forceinline__ float bf2f(short s) {
    unsigned u = ((unsigned)(unsigned short)s) << 16;
    return __builtin_bit_cast(float, u);
}
__device__ __forceinline__ unsigned cvtpk2(float x, float y) {
    return ((unsigned)(unsigned short)f2bf(x)) |
           (((unsigned)(unsigned short)f2bf(y)) << 16);
}
__device__ __forceinline__ bf16x8 pack8(f32x4 a, f32x4 b) {
    u32x4 r = {cvtpk2(a[0], a[1]), cvtpk2(a[2], a[3]),
               cvtpk2(b[0], b[1]), cvtpk2(b[2], b[3])};
    return __builtin_bit_cast(bf16x8, r);
}
__device__ __forceinline__ void split_bf(float w, short& hi, short& lo) {
    hi = f2bf(w);
    lo = f2bf(w - bf2f(hi));
}

// ---------------------------------------------------------------------------
// Kernel 0: split Wa into hi/lo bf16 (row-major + transposed); Ua -> bf16 RM.
__global__ void prep_kernel(const float* __restrict__ Wa, const float* __restrict__ Ua,
                            short* __restrict__ hiRM, short* __restrict__ loRM,
                            short* __restrict__ hiT, short* __restrict__ loT,
                            short* __restrict__ ua_b) {
    int i = blockIdx.x * blockDim.x + threadIdx.x;
    if (i >= POWN) return;
    int r = i >> 9, c = i & 511;
    short hi, lo;
    split_bf(Wa[i], hi, lo);
    hiRM[i] = hi; loRM[i] = lo;
    hiT[c * 512 + r] = hi;
    loT[c * 512 + r] = lo;
    ua_b[i] = f2bf(Ua[i]);
}

__device__ __forceinline__ int sel4(int4 v, int i) {
    int r = v.x;
    if (i == 1) r = v.y;
    if (i == 2) r = v.z;
    if (i == 3) r = v.w;
    return r;
}

// ---------------------------------------------------------------------------
// Kernel 1: matrix-power products (unchanged from R5 — tiny, works).
__global__ __launch_bounds__(256)
void powmul_kernel(short* __restrict__ hiRM, short* __restrict__ loRM,
                   short* __restrict__ hiT, short* __restrict__ loT,
                   int4 aS, int4 bS, int4 dS) {
    const int p = blockIdx.z;
    const int as = sel4(aS, p), bs = sel4(bS, p), ds = sel4(dS, p);
    const short* Ah = hiRM + (size_t)as * POWN;
    const short* Al = loRM + (size_t)as * POWN;
    const short* Bh = hiT + (size_t)bs * POWN;
    const short* Bl = loT + (size_t)bs * POWN;

    const int tid = threadIdx.x, lane = tid & 63, w = tid >> 6;
    const int l15 = lane & 15, lg = lane >> 4;
    const int row = blockIdx.x * 64 + w * 16 + l15;
    const int colb = blockIdx.y * 64;

    f32x4 acc[4];
#pragma unroll
    for (int nf = 0; nf < 4; ++nf) acc[nf] = (f32x4){0.f, 0.f, 0.f, 0.f};

    for (int ch = 0; ch < 16; ++ch) {
        const int e0 = ch * 32 + lg * 8;
        bf16x8 ah = *(const bf16x8*)(Ah + row * 512 + e0);
        bf16x8 al = *(const bf16x8*)(Al + row * 512 + e0);
#pragma unroll
        for (int nf = 0; nf < 4; ++nf) {
            const int col = colb + nf * 16 + l15;
            bf16x8 bh = *(const bf16x8*)(Bh + col * 512 + e0);
            bf16x8 bl = *(const bf16x8*)(Bl + col * 512 + e0);
            acc[nf] = __builtin_amdgcn_mfma_f32_16x16x32_bf16(ah, bh, acc[nf], 0, 0, 0);
            acc[nf] = __builtin_amdgcn_mfma_f32_16x16x32_bf16(ah, bl, acc[nf], 0, 0, 0);
            acc[nf] = __builtin_amdgcn_mfma_f32_16x16x32_bf16(al, bh, acc[nf], 0, 0, 0);
        }
    }

    short* Dh = hiRM + (size_t)ds * POWN;
    short* Dl = loRM + (size_t)ds * POWN;
#pragma unroll
    for (int nf = 0; nf < 4; ++nf)
#pragma unroll
        for (int j = 0; j < 4; ++j) {
            int rg = blockIdx.x * 64 + w * 16 + lg * 4 + j;
            int cg = colb + nf * 16 + l15;
            short hi, lo;
            split_bf(acc[nf][j], hi, lo);
            Dh[rg * 512 + cg] = hi;
            Dl[rg * 512 + cg] = lo;
            if (ds < 4) {
                hiT[(size_t)ds * POWN + cg * 512 + rg] = hi;
                loT[(size_t)ds * POWN + cg * 512 + rg] = lo;
            }
        }
}

// ---------------------------------------------------------------------------
// Kernel 2: reorder 17 RM bf16 matrices into MFMA-B-fragment layout:
//   swz[ch(16)][cb(32)][lane(64)][8] ; element (h,k): cb=h>>4, l15=h&15,
//   ch=k>>5, lg=(k>>3)&3, j=k&7, lane=lg*16+l15.
// Reads coalesced (src-linear), writes scattered 16B (tiny: 8.5 MB total).
__global__ __launch_bounds__(256)
void swz_pow_kernel(const short* __restrict__ pow_hi, const short* __restrict__ pow_lo,
                    const short* __restrict__ ua_b,
                    short* __restrict__ swz_hi, short* __restrict__ swz_lo,
                    short* __restrict__ swz_ua) {
    const int m = blockIdx.y;
    const short* src;
    short* dst;
    if (m < 8)       { src = pow_hi + (size_t)m * POWN;       dst = swz_hi + (size_t)m * POWN; }
    else if (m < 16) { src = pow_lo + (size_t)(m - 8) * POWN; dst = swz_lo + (size_t)(m - 8) * POWN; }
    else             { src = ua_b;                             dst = swz_ua; }

#pragma unroll
    for (int i = 0; i < 8; ++i) {
        int c = blockIdx.x * 2048 + i * 256 + threadIdx.x;   // 16B chunk index, 0..32767
        bf16x8 v = *(const bf16x8*)(src + c * 8);            // coalesced
        int ch = (c >> 2) & 15;
        int lg = c & 3;
        int cb = c >> 10;
        int l15 = (c >> 6) & 15;
        int lane = lg * 16 + l15;
        *(bf16x8*)(dst + ((size_t)(ch * 32 + cb) * 64 + lane) * 8) = v;
    }
}

// ---------------------------------------------------------------------------
// Kernel 3: query f32 -> bf16 in A-fragment layout, per 64-row block:
//   q_sw[blk][mf(4)][ch(16)][lane(64)][8] ; row r = mf*16+l15, k = ch*32+lg*8+j
// Via LDS reorder: coalesced read AND coalesced write.
__global__ __launch_bounds__(THREADS)
void q_prep_kernel(const float* __restrict__ query, short* __restrict__ q_sw) {
    __shared__ short q_s[BM * 512];   // 64 KB, [r][s^(r&7)] 16B slots
    const int tid = threadIdx.x;
    const long rbase = (long)blockIdx.x * BM;

#pragma unroll
    for (int i = 0; i < 4; ++i) {
        int idx = tid + i * THREADS;          // 4096 chunks
        int r = idx >> 6, s = idx & 63;
        const float* qp = query + (rbase + r) * HID + s * 8;
        f32x4 a = *(const f32x4*)qp;
        f32x4 b = *(const f32x4*)(qp + 4);
        *(bf16x8*)&q_s[(r * 64 + (s ^ (r & 7))) * 8] = pack8(a, b);
    }
    __syncthreads();
    short* dst = q_sw + (size_t)blockIdx.x * (BM * 512);
#pragma unroll
    for (int i = 0; i < 4; ++i) {
        int d = tid + i * THREADS;            // 4096 chunks, fragment-linear
        int l15 = d & 15, lg = (d >> 4) & 3;
        int ch = (d >> 6) & 15, mf = (d >> 10) & 3;
        int r = mf * 16 + l15;
        int s = ch * 4 + lg;
        bf16x8 v = *(const bf16x8*)&q_s[(r * 64 + (s ^ (r & 7))) * 8];
        *(bf16x8*)(dst + (size_t)d * 8) = v;  // coalesced
    }
}

// ---------------------------------------------------------------------------
// Kernel 4: main. 64 rows/block, 16 waves (1M x 16N), per wave 4mf x 2nf.
// All global loads coalesced (fragment-swizzled); topics staged per step in LDS.
__global__ __launch_bounds__(THREADS, 4)
void attn_main_kernel(const float* __restrict__ topics,
                      const float* __restrict__ cov,
                      const short* __restrict__ q_sw,
                      const short* __restrict__ swz_hi,
                      const short* __restrict__ swz_lo,
                      const short* __restrict__ swz_ua,
                      const float* __restrict__ va_w,
                      const float* __restrict__ va_b,
                      float* __restrict__ out_mt,
                      float* __restrict__ out_alpha) {
    __shared__ short t_lds[BM * 512];        // 64 KB  [r][s^(r&7)] 16B slots
    __shared__ float scores_s[BM][KTOP];     // 2 KB
    __shared__ float alpha_s[BM][KTOP];      // 2 KB

    const int tid  = threadIdx.x;
    const int lane = tid & 63;
    const int wn   = tid >> 6;      // 0..15 : cols wn*32 + nf*16 + l15
    const int l15  = lane & 15;
    const int lg   = lane >> 4;
    const long rbase = (long)blockIdx.x * BM;

    if (tid < BM * KTOP) ((float*)scores_s)[tid] = 0.f;

    float va_reg[2];
#pragma unroll
    for (int nf = 0; nf < 2; ++nf) va_reg[nf] = va_w[wn * 32 + nf * 16 + l15];
    const float vab = va_b[0];

    const short* qbase = q_sw + (size_t)blockIdx.x * (BM * 512) + lane * 8;
    const int lane8 = lane * 8;

#pragma unroll 1
    for (int step = 0; step < KTOP; ++step) {
        // ---- stage topics[:, step, :] -> LDS (coalesced f32 reads) ----
        __syncthreads();
#pragma unroll
        for (int i = 0; i < 4; ++i) {
            int idx = tid + i * THREADS;
            int r = idx >> 6, s = idx & 63;
            const float* tp = topics + ((rbase + r) * KTOP + step) * EMB + s * 8;
            f32x4 a = *(const f32x4*)tp;
            f32x4 b = *(const f32x4*)(tp + 4);
            *(bf16x8*)&t_lds[(r * 64 + (s ^ (r & 7))) * 8] = pack8(a, b);
        }
        __syncthreads();

        const short* wh = swz_hi + (size_t)step * POWN;
        const short* wl = swz_lo + (size_t)step * POWN;

        f32x4 acc[4][2];
#pragma unroll
        for (int mf = 0; mf < 4; ++mf)
#pragma unroll
            for (int nf = 0; nf < 2; ++nf) acc[mf][nf] = (f32x4){0.f, 0.f, 0.f, 0.f};

        for (int ch = 0; ch < 16; ++ch) {
            bf16x8 qf[4], tf[4];
#pragma unroll
            for (int mf = 0; mf < 4; ++mf) {
                qf[mf] = *(const bf16x8*)(qbase + (size_t)(mf * 16 + ch) * 512);
                int r = mf * 16 + l15;
                int s = ch * 4 + lg;
                tf[mf] = *(const bf16x8*)&t_lds[(r * 64 + (s ^ (r & 7))) * 8];
            }
#pragma unroll
            for (int nf = 0; nf < 2; ++nf) {
                const size_t off = (size_t)((ch * 32 + wn * 2 + nf) * 512 + lane8);
                bf16x8 bh = *(const bf16x8*)(wh + off);
                bf16x8 bl = *(const bf16x8*)(wl + off);
                bf16x8 bu = *(const bf16x8*)(swz_ua + off);
#pragma unroll
                for (int mf = 0; mf < 4; ++mf) {
                    acc[mf][nf] = __builtin_amdgcn_mfma_f32_16x16x32_bf16(qf[mf], bh, acc[mf][nf], 0, 0, 0);
                    acc[mf][nf] = __builtin_amdgcn_mfma_f32_16x16x32_bf16(qf[mf], bl, acc[mf][nf], 0, 0, 0);
                    acc[mf][nf] = __builtin_amdgcn_mfma_f32_16x16x32_bf16(tf[mf], bu, acc[mf][nf], 0, 0, 0);
                }
            }
        }

        // ---- epilogue: partial score over this wave's 32 cols ----
        float part[4][4];
#pragma unroll
        for (int mf = 0; mf < 4; ++mf)
#pragma unroll
            for (int j = 0; j < 4; ++j) part[mf][j] = 0.f;
#pragma unroll
        for (int mf = 0; mf < 4; ++mf)
#pragma unroll
            for (int nf = 0; nf < 2; ++nf)
#pragma unroll
                for (int j = 0; j < 4; ++j) {
                    float x = acc[mf][nf][j];
                    float e = __expf(2.f * x);
                    float th = 1.f - 2.f / (e + 1.f);   // tanh(x)
                    part[mf][j] += th * va_reg[nf];
                }
#pragma unroll
        for (int m = 8; m >= 1; m >>= 1)
#pragma unroll
            for (int mf = 0; mf < 4; ++mf)
#pragma unroll
                for (int j = 0; j < 4; ++j)
                    part[mf][j] += __shfl_xor(part[mf][j], m, 64);
        if (l15 == 0) {   // lanes lg=0..3 cover rows mf*16 + lg*4 + j
#pragma unroll
            for (int mf = 0; mf < 4; ++mf)
#pragma unroll
                for (int j = 0; j < 4; ++j)
                    atomicAdd(&scores_s[mf * 16 + lg * 4 + j][step], part[mf][j]);
        }
    }

    __syncthreads();
    if (tid < BM * KTOP) {
        int r = tid >> 3, k = tid & 7;
        scores_s[r][k] = (scores_s[r][k] + vab) * cov[(rbase + r) * KTOP + k];
    }
    __syncthreads();
    if (tid < BM) {
        float mx = scores_s[tid][0];
#pragma unroll
        for (int k = 1; k < KTOP; ++k) mx = fmaxf(mx, scores_s[tid][k]);
        float e[KTOP], sum = 0.f;
#pragma unroll
        for (int k = 0; k < KTOP; ++k) { e[k] = __expf(scores_s[tid][k] - mx); sum += e[k]; }
#pragma unroll
        for (int k = 0; k < KTOP; ++k) {
            float a = e[k] / sum;
            alpha_s[tid][k] = a;
            out_alpha[(rbase + tid) * KTOP + k] = a;
        }
    }
    __syncthreads();

    // mt = sum_k alpha_k * topics[:,k,:]  (coalesced f32)
#pragma unroll 1
    for (int i = tid; i < BM * (EMB / 4); i += THREADS) {
        int r = i >> 7;
        int c4 = i & 127;
        const float* tb = topics + (rbase + r) * KTOP * EMB + c4 * 4;
        f32x4 acc = {0.f, 0.f, 0.f, 0.f};
#pragma unroll
        for (int k = 0; k < KTOP; ++k) {
            f32x4 t = *(const f32x4*)(tb + k * EMB);
            float a = alpha_s[r][k];
            acc[0] += t[0] * a;
            acc[1] += t[1] * a;
            acc[2] += t[2] * a;
            acc[3] += t[3] * a;
        }
        *(f32x4*)(out_mt + (rbase + r) * EMB + c4 * 4) = acc;
    }
}

extern "C" void kernel_launch(void* const* d_in, const int* in_sizes, int n_in,
                              void* d_out, int out_size, void* d_ws, size_t ws_size,
                              hipStream_t stream) {
    const float* query  = (const float*)d_in[0];
    const float* topics = (const float*)d_in[1];
    const float* cov    = (const float*)d_in[2];
    const float* Ua     = (const float*)d_in[3];
    const float* Wa     = (const float*)d_in[4];
    const float* va     = (const float*)d_in[5];
    const float* vab    = (const float*)d_in[6];

    const int Brows = in_sizes[0] / HID;   // 16384
    const int nblk  = Brows / BM;          // 256

    // ws layout (shorts): RM hi[8] | RM lo[8] | T hi[4] | T lo[4] | ua RM |
    //                     swz hi[8] | swz lo[8] | swz ua | q_sw     (~39 MB)
    short* pow_hi = (short*)d_ws;
    short* pow_lo = pow_hi + (size_t)8 * POWN;
    short* hiT    = pow_lo + (size_t)8 * POWN;
    short* loT    = hiT + (size_t)4 * POWN;
    short* ua_b   = loT + (size_t)4 * POWN;
    short* swz_hi = ua_b + POWN;
    short* swz_lo = swz_hi + (size_t)8 * POWN;
    short* swz_ua = swz_lo + (size_t)8 * POWN;
    short* q_sw   = swz_ua + POWN;

    float* out_mt    = (float*)d_out;
    float* out_alpha = out_mt + (size_t)Brows * EMB;

    prep_kernel<<<(POWN + 255) / 256, 256, 0, stream>>>(Wa, Ua, pow_hi, pow_lo,
                                                        hiT, loT, ua_b);
    // M2 = M1*M1
    powmul_kernel<<<dim3(8, 8, 1), 256, 0, stream>>>(pow_hi, pow_lo, hiT, loT,
        make_int4(0, 0, 0, 0), make_int4(0, 0, 0, 0), make_int4(1, 0, 0, 0));
    // M3 = M2*M1, M4 = M2*M2
    powmul_kernel<<<dim3(8, 8, 2), 256, 0, stream>>>(pow_hi, pow_lo, hiT, loT,
        make_int4(1, 1, 0, 0), make_int4(0, 1, 0, 0), make_int4(2, 3, 0, 0));
    // M5 = M4*M1, M6 = M4*M2, M7 = M3*M4, M8 = M4*M4
    powmul_kernel<<<dim3(8, 8, 4), 256, 0, stream>>>(pow_hi, pow_lo, hiT, loT,
        make_int4(3, 3, 2, 3), make_int4(0, 1, 3, 3), make_int4(4, 5, 6, 7));

    swz_pow_kernel<<<dim3(16, 17), 256, 0, stream>>>(pow_hi, pow_lo, ua_b,
                                                     swz_hi, swz_lo, swz_ua);
    q_prep_kernel<<<nblk, THREADS, 0, stream>>>(query, q_sw);

    attn_main_kernel<<<nblk, THREADS, 0, stream>>>(topics, cov, q_sw,
                                                   swz_hi, swz_lo, swz_ua,
                                                   va, vab, out_mt, out_alpha);
}